// Round 7
// baseline (568.847 us; speedup 1.0000x reference)
//
#include <hip/hip_runtime.h>

// ---------- bf16 helpers (raw ushort representation) ----------
__device__ __forceinline__ float bf2f(unsigned short u) {
    union { unsigned int i; float f; } v;
    v.i = ((unsigned int)u) << 16;
    return v.f;
}
__device__ __forceinline__ unsigned short f2bf(float f) {
    union { float f; unsigned int i; } v;
    v.f = f;
    unsigned int r = (v.i + 0x7fffu + ((v.i >> 16) & 1u)) >> 16;
    return (unsigned short)r;
}

typedef __attribute__((ext_vector_type(8))) short short8;
typedef __attribute__((ext_vector_type(4))) float floatx4;

#define GLOBAL_AS __attribute__((address_space(1)))
#define LDS_AS __attribute__((address_space(3)))

static constexpr int Bdim = 8;
static constexpr int Tdim = 2048;
static constexpr int Cdim = 1024;
static constexpr int Edim = 4096;
static constexpr int Mdim = Bdim * Tdim;  // 16384

// ---------- weight transpose + cast: src fp32 (K x N) -> dst bf16 (N x K) ----------
__global__ __launch_bounds__(256) void transpose_f2b(
    const float* __restrict__ src, unsigned short* __restrict__ dst, int K, int N) {
    __shared__ float tile[32][33];
    int n0 = blockIdx.x * 32;
    int k0 = blockIdx.y * 32;
    int tx = threadIdx.x & 31;
    int ty = threadIdx.x >> 5;  // 0..7
#pragma unroll
    for (int i = 0; i < 32; i += 8)
        tile[ty + i][tx] = src[(size_t)(k0 + ty + i) * N + n0 + tx];
    __syncthreads();
#pragma unroll
    for (int i = 0; i < 32; i += 8)
        dst[(size_t)(n0 + ty + i) * K + k0 + tx] = f2bf(tile[tx][ty + i]);
}

// ---------- rmsnorm1 inverse-RMS only: rinv[row] = rsqrt(mean(x^2)+eps) ----------
__global__ __launch_bounds__(256) void rms_inv_kernel(
    const float* __restrict__ x, float* __restrict__ rinv) {
    int row = blockIdx.x;
    int tid = threadIdx.x;
    float4 v = ((const float4*)(x + (size_t)row * Cdim))[tid];
    float s = v.x * v.x + v.y * v.y + v.z * v.z + v.w * v.w;
#pragma unroll
    for (int o = 32; o > 0; o >>= 1) s += __shfl_down(s, o, 64);
    __shared__ float ps[4];
    if ((tid & 63) == 0) ps[tid >> 6] = s;
    __syncthreads();
    if (tid == 0) {
        float tot = ps[0] + ps[1] + ps[2] + ps[3];
        rinv[row] = rsqrtf(tot * (1.0f / (float)Cdim) + 1e-6f);
    }
}

// ---------- cumsum phase A: per-chunk sums of y = x*rinv*w. 1024 blocks ----------
__global__ __launch_bounds__(256) void chunk_sums(
    const float* __restrict__ x, const float* __restrict__ rinv,
    const float* __restrict__ w, float* __restrict__ P) {
    int idx = blockIdx.x;
    int cb = idx & 3;
    int k = (idx >> 2) & 31;
    int b = idx >> 7;
    int c = cb * 256 + threadIdx.x;
    float wc = w[c];
    const float* base = x + ((size_t)b * Tdim + k * 64) * Cdim + c;
    const float* rbase = rinv + (size_t)b * Tdim + k * 64;
    float s = 0.f;
#pragma unroll 8
    for (int t = 0; t < 64; t++) s += base[(size_t)t * Cdim] * rbase[t];
    P[((size_t)b * 32 + k) * Cdim + c] = s * wc;
}

// ---------- cumsum phase C: prefix of chunk sums (folded, replaces chunk_scan) +
// rescan, divide by triangular scaler, emit bf16 state ----------
// Prefix: each block sums its <=31 preceding chunk sums directly (coalesced 1KB
// loads, hot in L2, 1024-block TLP) -- removes the 32-block latency-bound
// chunk_scan kernel (~64 serialized ~900cy global round-trips).
__global__ __launch_bounds__(256) void cumsum_state(
    const float* __restrict__ x, const float* __restrict__ rinv,
    const float* __restrict__ w, const float* __restrict__ P,
    unsigned short* __restrict__ state) {
    int idx = blockIdx.x;
    int cb = idx & 3;
    int k = (idx >> 2) & 31;
    int b = idx >> 7;
    int c = cb * 256 + threadIdx.x;
    float wc = w[c];
    const float* Pb = P + (size_t)b * 32 * Cdim + c;
    float acc = 0.f;
    for (int kk = 0; kk < k; kk++) acc += Pb[(size_t)kk * Cdim];
    const float* base = x + ((size_t)b * Tdim + k * 64) * Cdim + c;
    const float* rbase = rinv + (size_t)b * Tdim + k * 64;
    unsigned short* sbase = state + ((size_t)b * Tdim + k * 64) * Cdim + c;
#pragma unroll 4
    for (int t = 0; t < 64; t++) {
        acc += base[(size_t)t * Cdim] * rbase[t] * wc;
        int tt = k * 64 + t;
        float inv = 2.0f / ((float)(tt + 1) * (float)(tt + 2));
        sbase[(size_t)t * Cdim] = f2bf(acc * inv);
    }
}

// ---------- rmsnorm2: fp32 in -> bf16 out (GEMM A operand) ----------
__global__ __launch_bounds__(256) void rmsnorm_f2b(
    const float* __restrict__ x, const float* __restrict__ w,
    unsigned short* __restrict__ y) {
    int row = blockIdx.x;
    int tid = threadIdx.x;
    float4 v = ((const float4*)(x + (size_t)row * Cdim))[tid];
    float s = v.x * v.x + v.y * v.y + v.z * v.z + v.w * v.w;
#pragma unroll
    for (int o = 32; o > 0; o >>= 1) s += __shfl_down(s, o, 64);
    __shared__ float ps[4];
    if ((tid & 63) == 0) ps[tid >> 6] = s;
    __syncthreads();
    float tot = ps[0] + ps[1] + ps[2] + ps[3];
    float r = rsqrtf(tot * (1.0f / (float)Cdim) + 1e-6f);
    float4 w4 = ((const float4*)w)[tid];
    ushort4 o;
    o.x = f2bf(v.x * r * w4.x);
    o.y = f2bf(v.y * r * w4.y);
    o.z = f2bf(v.z * r * w4.z);
    o.w = f2bf(v.w * r * w4.w);
    ((ushort4*)(y + (size_t)row * Cdim))[tid] = o;
}

// ---------- A/B arm 1: bf16 MFMA GEMM 256x256, BK=64, 8-phase counted vmcnt ----
// r5 structure + ONE fix: ph3 gate vmcnt(2) -> vmcnt(4). At ph3 the outstanding
// queue (oldest->newest) is B(2j+1)[prev ph6/7]x4, A(2j+1)[ph0/1]x4, B(2j+2)[ph2/3]x4;
// ph4 needs exactly the 8 oldest drained -> vmcnt(4). vmcnt(2) additionally drained
// a load issued THIS phase (a full L2/HBM round-trip stall every 4 phases).
template <int EPI>
__global__ __launch_bounds__(512, 2) void gemm8(
    const unsigned short* __restrict__ A, const unsigned short* __restrict__ BT,
    const float* __restrict__ bias, const float* __restrict__ extra,
    void* __restrict__ Coutv, int N, int K) {
    __shared__ __attribute__((aligned(16))) unsigned short As[2][256 * 64];
    __shared__ __attribute__((aligned(16))) unsigned short Bs[2][256 * 64];

    int tid = threadIdx.x;
    int nbn = N >> 8;
    int id = blockIdx.x;
    int nwg = gridDim.x;
    if ((nwg & 7) == 0) id = (id & 7) * (nwg >> 3) + (id >> 3);
    int bn = id % nbn;
    int bm = id / nbn;

    int lane = tid & 63;
    int w = tid >> 6;     // 0..7
    int wm = w >> 2;      // 0..1 : rows wm*128 .. +127
    int wn = w & 3;       // 0..3 : cols wn*64 .. +63
    int lrow = lane & 15;
    int l4 = lane >> 4;   // 0..3
    int swz = lrow & 7;
    int wmB = wm * 128, wnB = wn * 64;

    const unsigned short* Abase = A + (size_t)bm * 256 * K;
    const unsigned short* Bbase = BT + (size_t)bn * 256 * K;

    int sr = tid >> 3;                 // row within 64x64 staging unit
    int col8 = (tid & 7) ^ (sr & 7);   // pre-swizzled source 8-elem column block

#define STAGE_A(sb, u, k0)                                                               \
    __builtin_amdgcn_global_load_lds(                                                    \
        (const GLOBAL_AS void*)(Abase + (size_t)((u) * 64 + sr) * K + (k0) + col8 * 8),  \
        (LDS_AS void*)(As[sb] + (u) * 4096 + tid * 8), 16, 0, 0)
#define STAGE_B(sb, u, k0)                                                               \
    __builtin_amdgcn_global_load_lds(                                                    \
        (const GLOBAL_AS void*)(Bbase + (size_t)((u) * 64 + sr) * K + (k0) + col8 * 8),  \
        (LDS_AS void*)(Bs[sb] + (u) * 4096 + tid * 8), 16, 0, 0)

#define LDA(cb, i, ks)                                                                   \
    (*(const short8*)(As[cb] + (wmB + (i) * 16 + lrow) * 64 + ((((ks) * 4 + l4) ^ swz) << 3)))
#define LDB(cb, jj, ks)                                                                  \
    (*(const short8*)(Bs[cb] + (wnB + (jj) * 16 + lrow) * 64 + ((((ks) * 4 + l4) ^ swz) << 3)))

#define PH_IN                                                                            \
    do {                                                                                 \
        __builtin_amdgcn_s_barrier();                                                    \
        __builtin_amdgcn_s_setprio(1);                                                   \
    } while (0)
#define PH_OUT                                                                           \
    do {                                                                                 \
        __builtin_amdgcn_s_setprio(0);                                                   \
        __builtin_amdgcn_s_barrier();                                                    \
    } while (0)

    floatx4 acc[8][4] = {};
    int nt = K >> 6;
    int nIter = nt >> 1;

    STAGE_A(0, 0, 0); STAGE_A(0, 1, 0); STAGE_A(0, 2, 0); STAGE_A(0, 3, 0);
    STAGE_B(0, 0, 0); STAGE_B(0, 1, 0); STAGE_B(0, 2, 0); STAGE_B(0, 3, 0);
    STAGE_B(1, 0, 64); STAGE_B(1, 1, 64); STAGE_B(1, 2, 64); STAGE_B(1, 3, 64);
    asm volatile("s_waitcnt vmcnt(4)" ::: "memory");
    __builtin_amdgcn_s_barrier();

    for (int j = 0; j < nIter; ++j) {
        int k1 = (2 * j + 1) << 6;
        int k2 = (2 * j + 2) << 6;
        int k3 = (2 * j + 3) << 6;
        bool nl = (j + 1 < nIter);

        short8 av[4], b0[4], b1[4];

        // ---- ph0 ----
#pragma unroll
        for (int i = 0; i < 4; i++) av[i] = LDA(0, i, 0);
#pragma unroll
        for (int i = 0; i < 4; i++) b0[i] = LDB(0, i, 0);
        STAGE_A(1, 0, k1); STAGE_A(1, 1, k1);
        PH_IN;
#pragma unroll
        for (int i = 0; i < 4; i++)
#pragma unroll
            for (int q = 0; q < 4; q++)
                acc[i][q] = __builtin_amdgcn_mfma_f32_16x16x32_bf16(av[i], b0[q], acc[i][q], 0, 0, 0);
        PH_OUT;

        // ---- ph1 ----
#pragma unroll
        for (int i = 0; i < 4; i++) av[i] = LDA(0, i, 1);
#pragma unroll
        for (int i = 0; i < 4; i++) b1[i] = LDB(0, i, 1);
        STAGE_A(1, 2, k1); STAGE_A(1, 3, k1);
        PH_IN;
#pragma unroll
        for (int i = 0; i < 4; i++)
#pragma unroll
            for (int q = 0; q < 4; q++)
                acc[i][q] = __builtin_amdgcn_mfma_f32_16x16x32_bf16(av[i], b1[q], acc[i][q], 0, 0, 0);
        PH_OUT;

        // ---- ph2 ----
#pragma unroll
        for (int i = 0; i < 4; i++) av[i] = LDA(0, 4 + i, 0);
        if (nl) { STAGE_B(0, 0, k2); STAGE_B(0, 1, k2); }
        PH_IN;
#pragma unroll
        for (int i = 0; i < 4; i++)
#pragma unroll
            for (int q = 0; q < 4; q++)
                acc[4 + i][q] = __builtin_amdgcn_mfma_f32_16x16x32_bf16(av[i], b0[q], acc[4 + i][q], 0, 0, 0);
        PH_OUT;

        // ---- ph3: vmcnt gate (FIXED: 4, the exact needed drain) ----
#pragma unroll
        for (int i = 0; i < 4; i++) av[i] = LDA(0, 4 + i, 1);
        if (nl) { STAGE_B(0, 2, k2); STAGE_B(0, 3, k2); }
        if (nl) asm volatile("s_waitcnt vmcnt(4)" ::: "memory");
        else    asm volatile("s_waitcnt vmcnt(0)" ::: "memory");
        PH_IN;
#pragma unroll
        for (int i = 0; i < 4; i++)
#pragma unroll
            for (int q = 0; q < 4; q++)
                acc[4 + i][q] = __builtin_amdgcn_mfma_f32_16x16x32_bf16(av[i], b1[q], acc[4 + i][q], 0, 0, 0);
        PH_OUT;

        // ---- ph4 ----
#pragma unroll
        for (int i = 0; i < 4; i++) av[i] = LDA(1, i, 0);
#pragma unroll
        for (int i = 0; i < 4; i++) b0[i] = LDB(1, i, 0);
        if (nl) { STAGE_A(0, 0, k2); STAGE_A(0, 1, k2); }
        PH_IN;
#pragma unroll
        for (int i = 0; i < 4; i++)
#pragma unroll
            for (int q = 0; q < 4; q++)
                acc[i][q] = __builtin_amdgcn_mfma_f32_16x16x32_bf16(av[i], b0[q], acc[i][q], 0, 0, 0);
        PH_OUT;

        // ---- ph5 ----
#pragma unroll
        for (int i = 0; i < 4; i++) av[i] = LDA(1, i, 1);
#pragma unroll
        for (int i = 0; i < 4; i++) b1[i] = LDB(1, i, 1);
        if (nl) { STAGE_A(0, 2, k2); STAGE_A(0, 3, k2); }
        PH_IN;
#pragma unroll
        for (int i = 0; i < 4; i++)
#pragma unroll
            for (int q = 0; q < 4; q++)
                acc[i][q] = __builtin_amdgcn_mfma_f32_16x16x32_bf16(av[i], b1[q], acc[i][q], 0, 0, 0);
        PH_OUT;

        // ---- ph6 ----
#pragma unroll
        for (int i = 0; i < 4; i++) av[i] = LDA(1, 4 + i, 0);
        if (nl) { STAGE_B(1, 0, k3); STAGE_B(1, 1, k3); }
        PH_IN;
#pragma unroll
        for (int i = 0; i < 4; i++)
#pragma unroll
            for (int q = 0; q < 4; q++)
                acc[4 + i][q] = __builtin_amdgcn_mfma_f32_16x16x32_bf16(av[i], b0[q], acc[4 + i][q], 0, 0, 0);
        PH_OUT;

        // ---- ph7: vmcnt gate ----
#pragma unroll
        for (int i = 0; i < 4; i++) av[i] = LDA(1, 4 + i, 1);
        if (nl) { STAGE_B(1, 2, k3); STAGE_B(1, 3, k3); }
        if (nl) asm volatile("s_waitcnt vmcnt(4)" ::: "memory");
        PH_IN;
#pragma unroll
        for (int i = 0; i < 4; i++)
#pragma unroll
            for (int q = 0; q < 4; q++)
                acc[4 + i][q] = __builtin_amdgcn_mfma_f32_16x16x32_bf16(av[i], b1[q], acc[4 + i][q], 0, 0, 0);
        PH_OUT;
    }
#undef STAGE_A
#undef STAGE_B
#undef LDA
#undef LDB
#undef PH_IN
#undef PH_OUT

    asm volatile("s_waitcnt vmcnt(0)" ::: "memory");

    int crow = l4 << 2;
    int ccol = lane & 15;
#pragma unroll
    for (int i = 0; i < 8; i++) {
#pragma unroll
        for (int q = 0; q < 4; q++) {
            size_t gm = (size_t)bm * 256 + wmB + i * 16 + crow;
            size_t gn = (size_t)bn * 256 + wnB + q * 16 + ccol;
            float bsv = bias[gn];
#pragma unroll
            for (int r = 0; r < 4; r++) {
                float v = acc[i][q][r] + bsv;
                size_t off = (gm + r) * (size_t)N + gn;
                if (EPI == 0) {
                    float g = 1.f / (1.f + __expf(-v));
                    ((float*)Coutv)[off] = g * extra[off];
                } else if (EPI == 1) {
                    ((unsigned short*)Coutv)[off] = f2bf(v > 0.f ? v : 0.f);
                } else {
                    ((float*)Coutv)[off] = v + extra[off];
                }
            }
        }
    }
}

// ---------- A/B arm 2: m97-style GEMM. 128x128 tile, BK=32, 256 thr, dbuf ----------
// Round-0 structure (proven 912-TF-class at 4096^3 in the guide's ladder) with its
// two measured deficits fixed:
//  * bank conflicts (was 1.68e7): read slot swizzled by (row>>1)&3. Derivation:
//    [128][32]-bf16 rows are 64B; lanes 0-15 read 16 consecutive rows at one 16B
//    slot -> bank group g=(4*(row&1)+slot)%8 gave 2 groups for 16 lanes = 8-way.
//    slot^=(row>>1)&3 makes (parity,slot) take all 8 values over rows 0..7 ->
//    2 lanes/bank = free (m136). Staging pre-swizzles the SOURCE column so the
//    linear global_load_lds dest lands swizzled (both-sides rule).
//  * scattered fetch (was 568MB): XCD-aware block swizzle.
// 32KB LDS + ~160 regs -> ~3 blocks/CU: TLP hides the per-barrier vmcnt(0) drain
// (m114 wave-overlap), unlike the 1-block/CU 256x256 arm.
template <int EPI>
__global__ __launch_bounds__(256, 3) void gemm97(
    const unsigned short* __restrict__ A, const unsigned short* __restrict__ BT,
    const float* __restrict__ bias, const float* __restrict__ extra,
    void* __restrict__ Coutv, int N, int K) {
    __shared__ __attribute__((aligned(16))) unsigned short As[2][128 * 32];
    __shared__ __attribute__((aligned(16))) unsigned short Bs[2][128 * 32];

    int tid = threadIdx.x;
    int nbn = N >> 7;
    int id = blockIdx.x;
    int nwg = gridDim.x;
    if ((nwg & 7) == 0) id = (id & 7) * (nwg >> 3) + (id >> 3);
    int bn = id % nbn;
    int bm = id / nbn;

    int wave = tid >> 6, lane = tid & 63;
    int wm = (wave & 1) * 64, wn = (wave >> 1) * 64;
    int lrow = lane & 15;
    // swizzled 8-elem slot: (lane>>4) ^ ((row>>1)&3); row = base16 + lrow with
    // base16 a multiple of 16 -> (row>>1)&3 == (lrow>>1)&3 (lane-constant).
    int lk = (((lane >> 4) ^ ((lrow >> 1) & 3)) << 3);

    const unsigned short* Abase = A + (size_t)bm * 128 * K;
    const unsigned short* Bbase = BT + (size_t)bn * 128 * K;

    floatx4 acc[4][4] = {};

    // staging: thread q covers row q>>2, slot q&3; global source column block is
    // pre-swizzled so physical LDS slot ps holds logical slot ps^((row>>1)&3).
    int qrow = tid >> 2;
    int qcol = (((tid & 3) ^ ((qrow >> 1) & 3)) << 3);
    const unsigned short* ArowLo = Abase + (size_t)qrow * K + qcol;
    const unsigned short* ArowHi = Abase + (size_t)(qrow + 64) * K + qcol;  // (qrow+64)>>1 &3 unchanged
    const unsigned short* BrowLo = Bbase + (size_t)qrow * K + qcol;
    const unsigned short* BrowHi = Bbase + (size_t)(qrow + 64) * K + qcol;

#define STAGE(buf, koff)                                                                   \
    do {                                                                                   \
        __builtin_amdgcn_global_load_lds((const GLOBAL_AS void*)(ArowLo + (koff)),         \
                                         (LDS_AS void*)(As[buf] + (size_t)tid * 8), 16, 0, 0); \
        __builtin_amdgcn_global_load_lds((const GLOBAL_AS void*)(ArowHi + (koff)),         \
                                         (LDS_AS void*)(As[buf] + (size_t)(tid + 256) * 8), 16, 0, 0); \
        __builtin_amdgcn_global_load_lds((const GLOBAL_AS void*)(BrowLo + (koff)),         \
                                         (LDS_AS void*)(Bs[buf] + (size_t)tid * 8), 16, 0, 0); \
        __builtin_amdgcn_global_load_lds((const GLOBAL_AS void*)(BrowHi + (koff)),         \
                                         (LDS_AS void*)(Bs[buf] + (size_t)(tid + 256) * 8), 16, 0, 0); \
    } while (0)

    int iters = K >> 5;
    STAGE(0, 0);
    for (int k = 0; k < iters; k++) {
        int cur = k & 1;
        __syncthreads();  // drains DMA (buf[cur] valid) + joins waves
        if (k + 1 < iters) STAGE(cur ^ 1, (k + 1) << 5);

        short8 af[4], bfr[4];
#pragma unroll
        for (int i = 0; i < 4; i++)
            af[i] = *(const short8*)(As[cur] + (wm + i * 16 + lrow) * 32 + lk);
#pragma unroll
        for (int j = 0; j < 4; j++)
            bfr[j] = *(const short8*)(Bs[cur] + (wn + j * 16 + lrow) * 32 + lk);
#pragma unroll
        for (int i = 0; i < 4; i++)
#pragma unroll
            for (int j = 0; j < 4; j++)
                acc[i][j] = __builtin_amdgcn_mfma_f32_16x16x32_bf16(af[i], bfr[j], acc[i][j], 0, 0, 0);
    }
#undef STAGE

    int crow = (lane >> 4) * 4;
    int ccol = lane & 15;
#pragma unroll
    for (int i = 0; i < 4; i++) {
#pragma unroll
        for (int j = 0; j < 4; j++) {
            size_t gm = (size_t)bm * 128 + wm + i * 16 + crow;
            size_t gn = (size_t)bn * 128 + wn + j * 16 + ccol;
            float bsv = bias[gn];
#pragma unroll
            for (int r = 0; r < 4; r++) {
                float v = acc[i][j][r] + bsv;
                size_t off = (gm + r) * (size_t)N + gn;
                if (EPI == 0) {
                    float g = 1.f / (1.f + __expf(-v));
                    ((float*)Coutv)[off] = g * extra[off];
                } else if (EPI == 1) {
                    ((unsigned short*)Coutv)[off] = f2bf(v > 0.f ? v : 0.f);
                } else {
                    ((float*)Coutv)[off] = v + extra[off];
                }
            }
        }
    }
}

// ---------- launch ----------
extern "C" void kernel_launch(void* const* d_in, const int* in_sizes, int n_in,
                              void* d_out, int out_size, void* d_ws, size_t ws_size,
                              hipStream_t stream) {
    const float* x   = (const float*)d_in[0];  // (B,T,C) fp32
    const float* n1w = (const float*)d_in[1];  // (C)
    const float* w1  = (const float*)d_in[2];  // (C,C)
    const float* b1  = (const float*)d_in[3];  // (C)
    const float* n2w = (const float*)d_in[4];  // (C)
    const float* w21 = (const float*)d_in[5];  // (C,E)
    const float* b21 = (const float*)d_in[6];  // (E)
    const float* w22 = (const float*)d_in[7];  // (E,C)
    const float* b22 = (const float*)d_in[8];  // (C)
    float* out = (float*)d_out;                // (B,T,C) fp32

    char* ws = (char*)d_ws;
    const size_t MB = 1024ull * 1024ull;
    unsigned short* state = (unsigned short*)(ws);            // 32MB bf16; reused as hnorm
    unsigned short* w1T   = (unsigned short*)(ws + 32 * MB);  // 2MB  (C x C) bf16
    unsigned short* w21T  = (unsigned short*)(ws + 34 * MB);  // 8MB  (E x C) bf16
    unsigned short* w22T  = (unsigned short*)(ws + 42 * MB);  // 8MB  (C x E) bf16
    float* P              = (float*)(ws + 50 * MB);           // 1MB
    float* rinv           = (float*)(ws + 51 * MB);           // 64KB
    unsigned short* h     = (unsigned short*)(ws + 52 * MB);  // up to 128MB bf16 (sliced)
    float* out1 = out;  // gate*x lives in d_out (fp32); G3 reads then overwrites per-element

    int slice_rows = Mdim;
    while (52 * MB + (size_t)slice_rows * Edim * 2 > ws_size && slice_rows > 1024)
        slice_rows >>= 1;

    // weights -> bf16 (N x K)
    transpose_f2b<<<dim3(Cdim / 32, Cdim / 32), 256, 0, stream>>>(w1, w1T, Cdim, Cdim);
    transpose_f2b<<<dim3(Edim / 32, Cdim / 32), 256, 0, stream>>>(w21, w21T, Cdim, Edim);
    transpose_f2b<<<dim3(Cdim / 32, Edim / 32), 256, 0, stream>>>(w22, w22T, Edim, Cdim);

    // rmsnorm1 scale factors
    rms_inv_kernel<<<Mdim, 256, 0, stream>>>(x, rinv);

    // chunked cumsum of x*rinv*n1w over T (prefix folded into cumsum_state)
    chunk_sums<<<1024, 256, 0, stream>>>(x, rinv, n1w, P);
    cumsum_state<<<1024, 256, 0, stream>>>(x, rinv, n1w, P, state);

    // G1: out1 = sigmoid(state @ w1 + b1) * x   (fp32 out into d_out)
    gemm8<0><<<dim3((Mdim / 256) * (Cdim / 256)), 512, 0, stream>>>(
        state, w1T, b1, x, out1, Cdim, Cdim);

    // rmsnorm2(out1) -> bf16 hnorm (reuse state buffer)
    rmsnorm_f2b<<<Mdim, 256, 0, stream>>>(out1, n2w, state);

    // G2 (arm 1: 8-phase 256^2) / G3 (arm 2: m97-style 128^2) -- same FLOPs, A/B.
    for (int m0 = 0; m0 < Mdim; m0 += slice_rows) {
        gemm8<1><<<dim3((slice_rows / 256) * (Edim / 256)), 512, 0, stream>>>(
            state + (size_t)m0 * Cdim, w21T, b21, nullptr, h, Edim, Cdim);
        gemm97<2><<<dim3((slice_rows / 128) * (Cdim / 128)), 256, 0, stream>>>(
            h, w22T, b22, out1 + (size_t)m0 * Cdim, out + (size_t)m0 * Cdim,
            Cdim, Edim);
    }
}

// Round 8
// 563.256 us; speedup vs baseline: 1.0099x; 1.0099x over previous
//
#include <hip/hip_runtime.h>

// ---------- bf16 helpers (raw ushort representation) ----------
__device__ __forceinline__ float bf2f(unsigned short u) {
    union { unsigned int i; float f; } v;
    v.i = ((unsigned int)u) << 16;
    return v.f;
}
__device__ __forceinline__ unsigned short f2bf(float f) {
    union { float f; unsigned int i; } v;
    v.f = f;
    unsigned int r = (v.i + 0x7fffu + ((v.i >> 16) & 1u)) >> 16;
    return (unsigned short)r;
}

typedef __attribute__((ext_vector_type(8))) short short8;
typedef __attribute__((ext_vector_type(4))) float floatx4;

#define GLOBAL_AS __attribute__((address_space(1)))
#define LDS_AS __attribute__((address_space(3)))

static constexpr int Bdim = 8;
static constexpr int Tdim = 2048;
static constexpr int Cdim = 1024;
static constexpr int Edim = 4096;
static constexpr int Mdim = Bdim * Tdim;  // 16384

// ---------- weight transpose + cast: src fp32 (K x N) -> dst bf16 (N x K) ----------
__global__ __launch_bounds__(256) void transpose_f2b(
    const float* __restrict__ src, unsigned short* __restrict__ dst, int K, int N) {
    __shared__ float tile[32][33];
    int n0 = blockIdx.x * 32;
    int k0 = blockIdx.y * 32;
    int tx = threadIdx.x & 31;
    int ty = threadIdx.x >> 5;  // 0..7
#pragma unroll
    for (int i = 0; i < 32; i += 8)
        tile[ty + i][tx] = src[(size_t)(k0 + ty + i) * N + n0 + tx];
    __syncthreads();
#pragma unroll
    for (int i = 0; i < 32; i += 8)
        dst[(size_t)(n0 + ty + i) * K + k0 + tx] = f2bf(tile[tx][ty + i]);
}

// ---------- fused rmsnorm1-rinv + chunk sums: one HBM pass over x ----------
// Block = (b, k-chunk of 64 rows). Pass A: per-row sumsq (4 threads/row, shuffle
// reduce) -> rinv (LDS + global). Pass B: per-column sums of x*rinv over the 64
// rows, re-read L2/L3-hot (256KB chunk just touched). Replaces rms_inv (64MB HBM)
// + chunk_sums (64MB HBM) with ~64MB HBM + 64MB L2.
__global__ __launch_bounds__(256) void rms_chunk(
    const float* __restrict__ x, const float* __restrict__ w,
    float* __restrict__ rinv, float* __restrict__ P) {
    int k = blockIdx.x & 31;
    int b = blockIdx.x >> 5;
    int tid = threadIdx.x;
    const float* xb = x + ((size_t)b * Tdim + k * 64) * Cdim;
    __shared__ float rlds[64];

    // pass A: row r = tid>>2; 4 threads cover cols {c0+16*i}, c0=(tid&3)*4
    int r = tid >> 2;
    int c0 = (tid & 3) << 2;
    const float* row = xb + (size_t)r * Cdim;
    float s = 0.f;
#pragma unroll
    for (int i = 0; i < 64; i++) {
        float4 v = *(const float4*)(row + c0 + i * 16);
        s += v.x * v.x + v.y * v.y + v.z * v.z + v.w * v.w;
    }
    s += __shfl_xor(s, 1, 64);
    s += __shfl_xor(s, 2, 64);
    if ((tid & 3) == 0) {
        float ri = rsqrtf(s * (1.0f / (float)Cdim) + 1e-6f);
        rlds[r] = ri;
        rinv[(size_t)b * Tdim + k * 64 + r] = ri;
    }
    __syncthreads();

    // pass B: 4 columns per thread (c = tid + j*256), sum over 64 rows
    float acc4[4] = {0.f, 0.f, 0.f, 0.f};
#pragma unroll 4
    for (int t = 0; t < 64; t++) {
        float rt = rlds[t];
        const float* xr = xb + (size_t)t * Cdim;
#pragma unroll
        for (int j = 0; j < 4; j++) acc4[j] += xr[tid + j * 256] * rt;
    }
    float* Pr = P + ((size_t)b * 32 + k) * Cdim;
#pragma unroll
    for (int j = 0; j < 4; j++) Pr[tid + j * 256] = acc4[j] * w[tid + j * 256];
}

// ---------- cumsum phase C: prefix of chunk sums (folded) + rescan, divide by
// triangular scaler, emit bf16 state ----------
__global__ __launch_bounds__(256) void cumsum_state(
    const float* __restrict__ x, const float* __restrict__ rinv,
    const float* __restrict__ w, const float* __restrict__ P,
    unsigned short* __restrict__ state) {
    int idx = blockIdx.x;
    int cb = idx & 3;
    int k = (idx >> 2) & 31;
    int b = idx >> 7;
    int c = cb * 256 + threadIdx.x;
    float wc = w[c];
    const float* Pb = P + (size_t)b * 32 * Cdim + c;
    float acc = 0.f;
    for (int kk = 0; kk < k; kk++) acc += Pb[(size_t)kk * Cdim];
    const float* base = x + ((size_t)b * Tdim + k * 64) * Cdim + c;
    const float* rbase = rinv + (size_t)b * Tdim + k * 64;
    unsigned short* sbase = state + ((size_t)b * Tdim + k * 64) * Cdim + c;
#pragma unroll 4
    for (int t = 0; t < 64; t++) {
        acc += base[(size_t)t * Cdim] * rbase[t] * wc;
        int tt = k * 64 + t;
        float inv = 2.0f / ((float)(tt + 1) * (float)(tt + 2));
        sbase[(size_t)t * Cdim] = f2bf(acc * inv);
    }
}

// ---------- rmsnorm2: fp32 in -> bf16 out (GEMM A operand) ----------
__global__ __launch_bounds__(256) void rmsnorm_f2b(
    const float* __restrict__ x, const float* __restrict__ w,
    unsigned short* __restrict__ y) {
    int row = blockIdx.x;
    int tid = threadIdx.x;
    float4 v = ((const float4*)(x + (size_t)row * Cdim))[tid];
    float s = v.x * v.x + v.y * v.y + v.z * v.z + v.w * v.w;
#pragma unroll
    for (int o = 32; o > 0; o >>= 1) s += __shfl_down(s, o, 64);
    __shared__ float ps[4];
    if ((tid & 63) == 0) ps[tid >> 6] = s;
    __syncthreads();
    float tot = ps[0] + ps[1] + ps[2] + ps[3];
    float r = rsqrtf(tot * (1.0f / (float)Cdim) + 1e-6f);
    float4 w4 = ((const float4*)w)[tid];
    ushort4 o;
    o.x = f2bf(v.x * r * w4.x);
    o.y = f2bf(v.y * r * w4.y);
    o.z = f2bf(v.z * r * w4.z);
    o.w = f2bf(v.w * r * w4.w);
    ((ushort4*)(y + (size_t)row * Cdim))[tid] = o;
}

// ---------- bf16 MFMA GEMM 256x256, BK=64, 8-phase counted vmcnt (best arm) ----
// Best-measured structure (r5/r7): 512 threads = 8 waves (2M x 4N), per-wave
// 128x64, acc[8][4]; 2 LDS buffers; phase = {reads+stage | BAR | 16 MFMA | BAR};
// stagger ph0/1 A(2j+1), ph2/3 B(2j+2), ph4/5 A(2j+2), ph6/7 B(2j+3); gates
// vmcnt(4) at ph3/ph7 drain exactly the tiles needed next, leaving the 4 newest
// in flight. XOR-swizzled LDS via pre-swizzled global source (conflicts = 0).
template <int EPI>
__global__ __launch_bounds__(512, 2) void gemm8(
    const unsigned short* __restrict__ A, const unsigned short* __restrict__ BT,
    const float* __restrict__ bias, const float* __restrict__ extra,
    void* __restrict__ Coutv, int N, int K) {
    __shared__ __attribute__((aligned(16))) unsigned short As[2][256 * 64];
    __shared__ __attribute__((aligned(16))) unsigned short Bs[2][256 * 64];

    int tid = threadIdx.x;
    int nbn = N >> 8;
    int id = blockIdx.x;
    int nwg = gridDim.x;
    if ((nwg & 7) == 0) id = (id & 7) * (nwg >> 3) + (id >> 3);
    int bn = id % nbn;
    int bm = id / nbn;

    int lane = tid & 63;
    int w = tid >> 6;     // 0..7
    int wm = w >> 2;      // 0..1 : rows wm*128 .. +127
    int wn = w & 3;       // 0..3 : cols wn*64 .. +63
    int lrow = lane & 15;
    int l4 = lane >> 4;   // 0..3
    int swz = lrow & 7;
    int wmB = wm * 128, wnB = wn * 64;

    const unsigned short* Abase = A + (size_t)bm * 256 * K;
    const unsigned short* Bbase = BT + (size_t)bn * 256 * K;

    int sr = tid >> 3;                 // row within 64x64 staging unit
    int col8 = (tid & 7) ^ (sr & 7);   // pre-swizzled source 8-elem column block

#define STAGE_A(sb, u, k0)                                                               \
    __builtin_amdgcn_global_load_lds(                                                    \
        (const GLOBAL_AS void*)(Abase + (size_t)((u) * 64 + sr) * K + (k0) + col8 * 8),  \
        (LDS_AS void*)(As[sb] + (u) * 4096 + tid * 8), 16, 0, 0)
#define STAGE_B(sb, u, k0)                                                               \
    __builtin_amdgcn_global_load_lds(                                                    \
        (const GLOBAL_AS void*)(Bbase + (size_t)((u) * 64 + sr) * K + (k0) + col8 * 8),  \
        (LDS_AS void*)(Bs[sb] + (u) * 4096 + tid * 8), 16, 0, 0)

#define LDA(cb, i, ks)                                                                   \
    (*(const short8*)(As[cb] + (wmB + (i) * 16 + lrow) * 64 + ((((ks) * 4 + l4) ^ swz) << 3)))
#define LDB(cb, jj, ks)                                                                  \
    (*(const short8*)(Bs[cb] + (wnB + (jj) * 16 + lrow) * 64 + ((((ks) * 4 + l4) ^ swz) << 3)))

#define PH_IN                                                                            \
    do {                                                                                 \
        __builtin_amdgcn_s_barrier();                                                    \
        __builtin_amdgcn_s_setprio(1);                                                   \
    } while (0)
#define PH_OUT                                                                           \
    do {                                                                                 \
        __builtin_amdgcn_s_setprio(0);                                                   \
        __builtin_amdgcn_s_barrier();                                                    \
    } while (0)

    floatx4 acc[8][4] = {};
    int nt = K >> 6;
    int nIter = nt >> 1;

    STAGE_A(0, 0, 0); STAGE_A(0, 1, 0); STAGE_A(0, 2, 0); STAGE_A(0, 3, 0);
    STAGE_B(0, 0, 0); STAGE_B(0, 1, 0); STAGE_B(0, 2, 0); STAGE_B(0, 3, 0);
    STAGE_B(1, 0, 64); STAGE_B(1, 1, 64); STAGE_B(1, 2, 64); STAGE_B(1, 3, 64);
    asm volatile("s_waitcnt vmcnt(4)" ::: "memory");
    __builtin_amdgcn_s_barrier();

    for (int j = 0; j < nIter; ++j) {
        int k1 = (2 * j + 1) << 6;
        int k2 = (2 * j + 2) << 6;
        int k3 = (2 * j + 3) << 6;
        bool nl = (j + 1 < nIter);

        short8 av[4], b0[4], b1[4];

        // ---- ph0 ----
#pragma unroll
        for (int i = 0; i < 4; i++) av[i] = LDA(0, i, 0);
#pragma unroll
        for (int i = 0; i < 4; i++) b0[i] = LDB(0, i, 0);
        STAGE_A(1, 0, k1); STAGE_A(1, 1, k1);
        PH_IN;
#pragma unroll
        for (int i = 0; i < 4; i++)
#pragma unroll
            for (int q = 0; q < 4; q++)
                acc[i][q] = __builtin_amdgcn_mfma_f32_16x16x32_bf16(av[i], b0[q], acc[i][q], 0, 0, 0);
        PH_OUT;

        // ---- ph1 ----
#pragma unroll
        for (int i = 0; i < 4; i++) av[i] = LDA(0, i, 1);
#pragma unroll
        for (int i = 0; i < 4; i++) b1[i] = LDB(0, i, 1);
        STAGE_A(1, 2, k1); STAGE_A(1, 3, k1);
        PH_IN;
#pragma unroll
        for (int i = 0; i < 4; i++)
#pragma unroll
            for (int q = 0; q < 4; q++)
                acc[i][q] = __builtin_amdgcn_mfma_f32_16x16x32_bf16(av[i], b1[q], acc[i][q], 0, 0, 0);
        PH_OUT;

        // ---- ph2 ----
#pragma unroll
        for (int i = 0; i < 4; i++) av[i] = LDA(0, 4 + i, 0);
        if (nl) { STAGE_B(0, 0, k2); STAGE_B(0, 1, k2); }
        PH_IN;
#pragma unroll
        for (int i = 0; i < 4; i++)
#pragma unroll
            for (int q = 0; q < 4; q++)
                acc[4 + i][q] = __builtin_amdgcn_mfma_f32_16x16x32_bf16(av[i], b0[q], acc[4 + i][q], 0, 0, 0);
        PH_OUT;

        // ---- ph3: vmcnt gate (drain exactly the 8 oldest; keep 4 newest in flight) ----
#pragma unroll
        for (int i = 0; i < 4; i++) av[i] = LDA(0, 4 + i, 1);
        if (nl) { STAGE_B(0, 2, k2); STAGE_B(0, 3, k2); }
        if (nl) asm volatile("s_waitcnt vmcnt(4)" ::: "memory");
        else    asm volatile("s_waitcnt vmcnt(0)" ::: "memory");
        PH_IN;
#pragma unroll
        for (int i = 0; i < 4; i++)
#pragma unroll
            for (int q = 0; q < 4; q++)
                acc[4 + i][q] = __builtin_amdgcn_mfma_f32_16x16x32_bf16(av[i], b1[q], acc[4 + i][q], 0, 0, 0);
        PH_OUT;

        // ---- ph4 ----
#pragma unroll
        for (int i = 0; i < 4; i++) av[i] = LDA(1, i, 0);
#pragma unroll
        for (int i = 0; i < 4; i++) b0[i] = LDB(1, i, 0);
        if (nl) { STAGE_A(0, 0, k2); STAGE_A(0, 1, k2); }
        PH_IN;
#pragma unroll
        for (int i = 0; i < 4; i++)
#pragma unroll
            for (int q = 0; q < 4; q++)
                acc[i][q] = __builtin_amdgcn_mfma_f32_16x16x32_bf16(av[i], b0[q], acc[i][q], 0, 0, 0);
        PH_OUT;

        // ---- ph5 ----
#pragma unroll
        for (int i = 0; i < 4; i++) av[i] = LDA(1, i, 1);
#pragma unroll
        for (int i = 0; i < 4; i++) b1[i] = LDB(1, i, 1);
        if (nl) { STAGE_A(0, 2, k2); STAGE_A(0, 3, k2); }
        PH_IN;
#pragma unroll
        for (int i = 0; i < 4; i++)
#pragma unroll
            for (int q = 0; q < 4; q++)
                acc[i][q] = __builtin_amdgcn_mfma_f32_16x16x32_bf16(av[i], b1[q], acc[i][q], 0, 0, 0);
        PH_OUT;

        // ---- ph6 ----
#pragma unroll
        for (int i = 0; i < 4; i++) av[i] = LDA(1, 4 + i, 0);
        if (nl) { STAGE_B(1, 0, k3); STAGE_B(1, 1, k3); }
        PH_IN;
#pragma unroll
        for (int i = 0; i < 4; i++)
#pragma unroll
            for (int q = 0; q < 4; q++)
                acc[4 + i][q] = __builtin_amdgcn_mfma_f32_16x16x32_bf16(av[i], b0[q], acc[4 + i][q], 0, 0, 0);
        PH_OUT;

        // ---- ph7: vmcnt gate ----
#pragma unroll
        for (int i = 0; i < 4; i++) av[i] = LDA(1, 4 + i, 1);
        if (nl) { STAGE_B(1, 2, k3); STAGE_B(1, 3, k3); }
        if (nl) asm volatile("s_waitcnt vmcnt(4)" ::: "memory");
        PH_IN;
#pragma unroll
        for (int i = 0; i < 4; i++)
#pragma unroll
            for (int q = 0; q < 4; q++)
                acc[4 + i][q] = __builtin_amdgcn_mfma_f32_16x16x32_bf16(av[i], b1[q], acc[4 + i][q], 0, 0, 0);
        PH_OUT;
    }
#undef STAGE_A
#undef STAGE_B
#undef LDA
#undef LDB
#undef PH_IN
#undef PH_OUT

    asm volatile("s_waitcnt vmcnt(0)" ::: "memory");

    int crow = l4 << 2;
    int ccol = lane & 15;
#pragma unroll
    for (int i = 0; i < 8; i++) {
#pragma unroll
        for (int q = 0; q < 4; q++) {
            size_t gm = (size_t)bm * 256 + wmB + i * 16 + crow;
            size_t gn = (size_t)bn * 256 + wnB + q * 16 + ccol;
            float bsv = bias[gn];
#pragma unroll
            for (int r = 0; r < 4; r++) {
                float v = acc[i][q][r] + bsv;
                size_t off = (gm + r) * (size_t)N + gn;
                if (EPI == 0) {
                    float g = 1.f / (1.f + __expf(-v));
                    ((float*)Coutv)[off] = g * extra[off];
                } else if (EPI == 1) {
                    ((unsigned short*)Coutv)[off] = f2bf(v > 0.f ? v : 0.f);
                } else {
                    ((float*)Coutv)[off] = v + extra[off];
                }
            }
        }
    }
}

// ---------- launch ----------
extern "C" void kernel_launch(void* const* d_in, const int* in_sizes, int n_in,
                              void* d_out, int out_size, void* d_ws, size_t ws_size,
                              hipStream_t stream) {
    const float* x   = (const float*)d_in[0];  // (B,T,C) fp32
    const float* n1w = (const float*)d_in[1];  // (C)
    const float* w1  = (const float*)d_in[2];  // (C,C)
    const float* b1  = (const float*)d_in[3];  // (C)
    const float* n2w = (const float*)d_in[4];  // (C)
    const float* w21 = (const float*)d_in[5];  // (C,E)
    const float* b21 = (const float*)d_in[6];  // (E)
    const float* w22 = (const float*)d_in[7];  // (E,C)
    const float* b22 = (const float*)d_in[8];  // (C)
    float* out = (float*)d_out;                // (B,T,C) fp32

    char* ws = (char*)d_ws;
    const size_t MB = 1024ull * 1024ull;
    unsigned short* state = (unsigned short*)(ws);            // 32MB bf16; reused as hnorm
    unsigned short* w1T   = (unsigned short*)(ws + 32 * MB);  // 2MB  (C x C) bf16
    unsigned short* w21T  = (unsigned short*)(ws + 34 * MB);  // 8MB  (E x C) bf16
    unsigned short* w22T  = (unsigned short*)(ws + 42 * MB);  // 8MB  (C x E) bf16
    float* P              = (float*)(ws + 50 * MB);           // 1MB
    float* rinv           = (float*)(ws + 51 * MB);           // 64KB
    unsigned short* h     = (unsigned short*)(ws + 52 * MB);  // up to 128MB bf16 (sliced)
    float* out1 = out;  // gate*x lives in d_out (fp32); G3 reads then overwrites per-element

    int slice_rows = Mdim;
    while (52 * MB + (size_t)slice_rows * Edim * 2 > ws_size && slice_rows > 1024)
        slice_rows >>= 1;

    // weights -> bf16 (N x K)
    transpose_f2b<<<dim3(Cdim / 32, Cdim / 32), 256, 0, stream>>>(w1, w1T, Cdim, Cdim);
    transpose_f2b<<<dim3(Edim / 32, Cdim / 32), 256, 0, stream>>>(w21, w21T, Cdim, Edim);
    transpose_f2b<<<dim3(Cdim / 32, Edim / 32), 256, 0, stream>>>(w22, w22T, Edim, Cdim);

    // fused rmsnorm1-rinv + chunk sums (one HBM pass over x)
    rms_chunk<<<256, 256, 0, stream>>>(x, n1w, rinv, P);

    // cumsum with folded prefix + triangular scaler -> bf16 state
    cumsum_state<<<1024, 256, 0, stream>>>(x, rinv, n1w, P, state);

    // G1: out1 = sigmoid(state @ w1 + b1) * x   (fp32 out into d_out)
    gemm8<0><<<dim3((Mdim / 256) * (Cdim / 256)), 512, 0, stream>>>(
        state, w1T, b1, x, out1, Cdim, Cdim);

    // rmsnorm2(out1) -> bf16 hnorm (reuse state buffer)
    rmsnorm_f2b<<<Mdim, 256, 0, stream>>>(out1, n2w, state);

    // G2 / G3, both best-arm gemm8, sliced over M to bound the h buffer
    for (int m0 = 0; m0 < Mdim; m0 += slice_rows) {
        gemm8<1><<<dim3((slice_rows / 256) * (Edim / 256)), 512, 0, stream>>>(
            state + (size_t)m0 * Cdim, w21T, b21, nullptr, h, Edim, Cdim);
        gemm8<2><<<dim3((slice_rows / 256) * (Cdim / 256)), 512, 0, stream>>>(
            h, w22T, b22, out1 + (size_t)m0 * Cdim, out + (size_t)m0 * Cdim,
            Cdim, Edim);
    }
}

// Round 9
// 538.934 us; speedup vs baseline: 1.0555x; 1.0451x over previous
//
#include <hip/hip_runtime.h>

// ---------- bf16 helpers (raw ushort representation) ----------
__device__ __forceinline__ float bf2f(unsigned short u) {
    union { unsigned int i; float f; } v;
    v.i = ((unsigned int)u) << 16;
    return v.f;
}
__device__ __forceinline__ unsigned short f2bf(float f) {
    union { float f; unsigned int i; } v;
    v.f = f;
    unsigned int r = (v.i + 0x7fffu + ((v.i >> 16) & 1u)) >> 16;
    return (unsigned short)r;
}

typedef __attribute__((ext_vector_type(8))) short short8;
typedef __attribute__((ext_vector_type(4))) float floatx4;

#define GLOBAL_AS __attribute__((address_space(1)))
#define LDS_AS __attribute__((address_space(3)))

static constexpr int Bdim = 8;
static constexpr int Tdim = 2048;
static constexpr int Cdim = 1024;
static constexpr int Edim = 4096;
static constexpr int Mdim = Bdim * Tdim;  // 16384

// ---------- weight transpose + cast: src fp32 (K x N) -> dst bf16 (N x K) ----------
__global__ __launch_bounds__(256) void transpose_f2b(
    const float* __restrict__ src, unsigned short* __restrict__ dst, int K, int N) {
    __shared__ float tile[32][33];
    int n0 = blockIdx.x * 32;
    int k0 = blockIdx.y * 32;
    int tx = threadIdx.x & 31;
    int ty = threadIdx.x >> 5;  // 0..7
#pragma unroll
    for (int i = 0; i < 32; i += 8)
        tile[ty + i][tx] = src[(size_t)(k0 + ty + i) * N + n0 + tx];
    __syncthreads();
#pragma unroll
    for (int i = 0; i < 32; i += 8)
        dst[(size_t)(n0 + ty + i) * K + k0 + tx] = f2bf(tile[tx][ty + i]);
}

// ---------- fused rmsnorm1-rinv + chunk sums: one HBM pass over x ----------
__global__ __launch_bounds__(256) void rms_chunk(
    const float* __restrict__ x, const float* __restrict__ w,
    float* __restrict__ rinv, float* __restrict__ P) {
    int k = blockIdx.x & 31;
    int b = blockIdx.x >> 5;
    int tid = threadIdx.x;
    const float* xb = x + ((size_t)b * Tdim + k * 64) * Cdim;
    __shared__ float rlds[64];

    // pass A: row r = tid>>2; 4 threads cover cols {c0+16*i}, c0=(tid&3)*4
    int r = tid >> 2;
    int c0 = (tid & 3) << 2;
    const float* row = xb + (size_t)r * Cdim;
    float s = 0.f;
#pragma unroll
    for (int i = 0; i < 64; i++) {
        float4 v = *(const float4*)(row + c0 + i * 16);
        s += v.x * v.x + v.y * v.y + v.z * v.z + v.w * v.w;
    }
    s += __shfl_xor(s, 1, 64);
    s += __shfl_xor(s, 2, 64);
    if ((tid & 3) == 0) {
        float ri = rsqrtf(s * (1.0f / (float)Cdim) + 1e-6f);
        rlds[r] = ri;
        rinv[(size_t)b * Tdim + k * 64 + r] = ri;
    }
    __syncthreads();

    // pass B: 4 columns per thread (c = tid + j*256), sum over 64 rows
    float acc4[4] = {0.f, 0.f, 0.f, 0.f};
#pragma unroll 4
    for (int t = 0; t < 64; t++) {
        float rt = rlds[t];
        const float* xr = xb + (size_t)t * Cdim;
#pragma unroll
        for (int j = 0; j < 4; j++) acc4[j] += xr[tid + j * 256] * rt;
    }
    float* Pr = P + ((size_t)b * 32 + k) * Cdim;
#pragma unroll
    for (int j = 0; j < 4; j++) Pr[tid + j * 256] = acc4[j] * w[tid + j * 256];
}

// ---------- cumsum phase C: folded prefix + rescan + triangular scaler -> bf16 ----------
__global__ __launch_bounds__(256) void cumsum_state(
    const float* __restrict__ x, const float* __restrict__ rinv,
    const float* __restrict__ w, const float* __restrict__ P,
    unsigned short* __restrict__ state) {
    int idx = blockIdx.x;
    int cb = idx & 3;
    int k = (idx >> 2) & 31;
    int b = idx >> 7;
    int c = cb * 256 + threadIdx.x;
    float wc = w[c];
    const float* Pb = P + (size_t)b * 32 * Cdim + c;
    float acc = 0.f;
    for (int kk = 0; kk < k; kk++) acc += Pb[(size_t)kk * Cdim];
    const float* base = x + ((size_t)b * Tdim + k * 64) * Cdim + c;
    const float* rbase = rinv + (size_t)b * Tdim + k * 64;
    unsigned short* sbase = state + ((size_t)b * Tdim + k * 64) * Cdim + c;
#pragma unroll 4
    for (int t = 0; t < 64; t++) {
        acc += base[(size_t)t * Cdim] * rbase[t] * wc;
        int tt = k * 64 + t;
        float inv = 2.0f / ((float)(tt + 1) * (float)(tt + 2));
        sbase[(size_t)t * Cdim] = f2bf(acc * inv);
    }
}

// ---------- rmsnorm2: fp32 in -> bf16 out (GEMM A operand) ----------
__global__ __launch_bounds__(256) void rmsnorm_f2b(
    const float* __restrict__ x, const float* __restrict__ w,
    unsigned short* __restrict__ y) {
    int row = blockIdx.x;
    int tid = threadIdx.x;
    float4 v = ((const float4*)(x + (size_t)row * Cdim))[tid];
    float s = v.x * v.x + v.y * v.y + v.z * v.z + v.w * v.w;
#pragma unroll
    for (int o = 32; o > 0; o >>= 1) s += __shfl_down(s, o, 64);
    __shared__ float ps[4];
    if ((tid & 63) == 0) ps[tid >> 6] = s;
    __syncthreads();
    float tot = ps[0] + ps[1] + ps[2] + ps[3];
    float r = rsqrtf(tot * (1.0f / (float)Cdim) + 1e-6f);
    float4 w4 = ((const float4*)w)[tid];
    ushort4 o;
    o.x = f2bf(v.x * r * w4.x);
    o.y = f2bf(v.y * r * w4.y);
    o.z = f2bf(v.z * r * w4.z);
    o.w = f2bf(v.w * r * w4.w);
    ((ushort4*)(y + (size_t)row * Cdim))[tid] = o;
}

// ---------- bf16 MFMA GEMM 256x256, BK=64, 4 MERGED phases per 2-K-tile iter ----
// r8's 8-phase structure with phase pairs merged: per phase {8-16 ds_read_b128;
// stage 4 gload_lds; [gate]; BAR; 32 MFMA; BAR}. Work per 2-K-tiles unchanged;
// barrier-pairs halve (16 -> 8) to amortize the measured ~800cyc/phase fixed
// rendezvous cost (r1-r5: schedule variants all pinned at ~1660cyc/phase while
// accountable work is ~850).
// Register audit (r3 spill lesson): max live frags 16 (a0,a1,b0,b1) = 64 VGPR,
// ~+16 vs r8 -> ~140 total, safe at 2 waves/SIMD (256 limit).
// Stagger per iter j (12-load queue, in-order retirement):
//  P0(tile 2j rows 0-63, ks0+1): stage A(2j+1) u0-u3
//  P1(tile 2j rows 64-127):      stage B(2j+2) u0-u3; gate vmcnt(4)
//     [drains A(2j+1)+B(2j+1) = the 8 oldest; leaves B(2j+2) in flight]
//  P2(tile 2j+1 rows 0-63):      stage A(2j+2) u0-u3
//  P3(tile 2j+1 rows 64-127):    stage B(2j+3) u0-u3; gate vmcnt(4)
// WAR: every restaged buffer's last ds_read finished >=1 barrier before the
// overwriting stage (reads feed the preceding phase's MFMA).
template <int EPI>
__global__ __launch_bounds__(512, 2) void gemm8(
    const unsigned short* __restrict__ A, const unsigned short* __restrict__ BT,
    const float* __restrict__ bias, const float* __restrict__ extra,
    void* __restrict__ Coutv, int N, int K) {
    __shared__ __attribute__((aligned(16))) unsigned short As[2][256 * 64];
    __shared__ __attribute__((aligned(16))) unsigned short Bs[2][256 * 64];

    int tid = threadIdx.x;
    int nbn = N >> 8;
    int id = blockIdx.x;
    int nwg = gridDim.x;
    if ((nwg & 7) == 0) id = (id & 7) * (nwg >> 3) + (id >> 3);
    int bn = id % nbn;
    int bm = id / nbn;

    int lane = tid & 63;
    int w = tid >> 6;     // 0..7
    int wm = w >> 2;      // 0..1 : rows wm*128 .. +127
    int wn = w & 3;       // 0..3 : cols wn*64 .. +63
    int lrow = lane & 15;
    int l4 = lane >> 4;   // 0..3
    int swz = lrow & 7;
    int wmB = wm * 128, wnB = wn * 64;

    const unsigned short* Abase = A + (size_t)bm * 256 * K;
    const unsigned short* Bbase = BT + (size_t)bn * 256 * K;

    int sr = tid >> 3;                 // row within 64x64 staging unit
    int col8 = (tid & 7) ^ (sr & 7);   // pre-swizzled source 8-elem column block

#define STAGE_A(sb, u, k0)                                                               \
    __builtin_amdgcn_global_load_lds(                                                    \
        (const GLOBAL_AS void*)(Abase + (size_t)((u) * 64 + sr) * K + (k0) + col8 * 8),  \
        (LDS_AS void*)(As[sb] + (u) * 4096 + tid * 8), 16, 0, 0)
#define STAGE_B(sb, u, k0)                                                               \
    __builtin_amdgcn_global_load_lds(                                                    \
        (const GLOBAL_AS void*)(Bbase + (size_t)((u) * 64 + sr) * K + (k0) + col8 * 8),  \
        (LDS_AS void*)(Bs[sb] + (u) * 4096 + tid * 8), 16, 0, 0)

#define LDA(cb, i, ks)                                                                   \
    (*(const short8*)(As[cb] + (wmB + (i) * 16 + lrow) * 64 + ((((ks) * 4 + l4) ^ swz) << 3)))
#define LDB(cb, jj, ks)                                                                  \
    (*(const short8*)(Bs[cb] + (wnB + (jj) * 16 + lrow) * 64 + ((((ks) * 4 + l4) ^ swz) << 3)))

    // 32-MFMA merged cluster: ks=0 sweep then ks=1 sweep (16 indep accs -> ILP)
#define MM32(R)                                                                          \
    do {                                                                                 \
        __builtin_amdgcn_s_setprio(1);                                                   \
        _Pragma("unroll") for (int i_ = 0; i_ < 4; i_++)                                 \
            _Pragma("unroll") for (int q_ = 0; q_ < 4; q_++)                             \
                acc[(R) + i_][q_] = __builtin_amdgcn_mfma_f32_16x16x32_bf16(             \
                    a0[i_], b0[q_], acc[(R) + i_][q_], 0, 0, 0);                         \
        _Pragma("unroll") for (int i_ = 0; i_ < 4; i_++)                                 \
            _Pragma("unroll") for (int q_ = 0; q_ < 4; q_++)                             \
                acc[(R) + i_][q_] = __builtin_amdgcn_mfma_f32_16x16x32_bf16(             \
                    a1[i_], b1[q_], acc[(R) + i_][q_], 0, 0, 0);                         \
        __builtin_amdgcn_s_setprio(0);                                                   \
    } while (0)

#define BAR __builtin_amdgcn_s_barrier()

    floatx4 acc[8][4] = {};
    int nt = K >> 6;
    int nIter = nt >> 1;

    // prologue: A(0), B(0) fully; B(1) fully. vmcnt(4): tile 0 landed, B(1) in flight.
    STAGE_A(0, 0, 0); STAGE_A(0, 1, 0); STAGE_A(0, 2, 0); STAGE_A(0, 3, 0);
    STAGE_B(0, 0, 0); STAGE_B(0, 1, 0); STAGE_B(0, 2, 0); STAGE_B(0, 3, 0);
    STAGE_B(1, 0, 64); STAGE_B(1, 1, 64); STAGE_B(1, 2, 64); STAGE_B(1, 3, 64);
    asm volatile("s_waitcnt vmcnt(4)" ::: "memory");
    BAR;

    for (int j = 0; j < nIter; ++j) {
        int k1 = (2 * j + 1) << 6;
        int k2 = (2 * j + 2) << 6;
        int k3 = (2 * j + 3) << 6;
        bool nl = (j + 1 < nIter);

        short8 a0[4], a1[4], b0[4], b1[4];

        // ---- P0: tile 2j, rows 0-63, ks=0+1 (16 reads); stage A(2j+1) ----
#pragma unroll
        for (int i = 0; i < 4; i++) a0[i] = LDA(0, i, 0);
#pragma unroll
        for (int i = 0; i < 4; i++) a1[i] = LDA(0, i, 1);
#pragma unroll
        for (int q = 0; q < 4; q++) b0[q] = LDB(0, q, 0);
#pragma unroll
        for (int q = 0; q < 4; q++) b1[q] = LDB(0, q, 1);
        STAGE_A(1, 0, k1); STAGE_A(1, 1, k1); STAGE_A(1, 2, k1); STAGE_A(1, 3, k1);
        BAR;
        MM32(0);
        BAR;

        // ---- P1: tile 2j, rows 64-127 (8 reads, b0/b1 reused); stage B(2j+2); gate ----
#pragma unroll
        for (int i = 0; i < 4; i++) a0[i] = LDA(0, 4 + i, 0);
#pragma unroll
        for (int i = 0; i < 4; i++) a1[i] = LDA(0, 4 + i, 1);
        if (nl) { STAGE_B(0, 0, k2); STAGE_B(0, 1, k2); STAGE_B(0, 2, k2); STAGE_B(0, 3, k2); }
        if (nl) asm volatile("s_waitcnt vmcnt(4)" ::: "memory");
        else    asm volatile("s_waitcnt vmcnt(0)" ::: "memory");
        BAR;
        MM32(4);
        BAR;

        // ---- P2: tile 2j+1, rows 0-63 (16 reads); stage A(2j+2) ----
#pragma unroll
        for (int i = 0; i < 4; i++) a0[i] = LDA(1, i, 0);
#pragma unroll
        for (int i = 0; i < 4; i++) a1[i] = LDA(1, i, 1);
#pragma unroll
        for (int q = 0; q < 4; q++) b0[q] = LDB(1, q, 0);
#pragma unroll
        for (int q = 0; q < 4; q++) b1[q] = LDB(1, q, 1);
        if (nl) { STAGE_A(0, 0, k2); STAGE_A(0, 1, k2); STAGE_A(0, 2, k2); STAGE_A(0, 3, k2); }
        BAR;
        MM32(0);
        BAR;

        // ---- P3: tile 2j+1, rows 64-127 (8 reads); stage B(2j+3); gate ----
#pragma unroll
        for (int i = 0; i < 4; i++) a0[i] = LDA(1, 4 + i, 0);
#pragma unroll
        for (int i = 0; i < 4; i++) a1[i] = LDA(1, 4 + i, 1);
        if (nl) { STAGE_B(1, 0, k3); STAGE_B(1, 1, k3); STAGE_B(1, 2, k3); STAGE_B(1, 3, k3); }
        if (nl) asm volatile("s_waitcnt vmcnt(4)" ::: "memory");
        BAR;
        MM32(4);
        BAR;
    }
#undef STAGE_A
#undef STAGE_B
#undef LDA
#undef LDB
#undef MM32
#undef BAR

    asm volatile("s_waitcnt vmcnt(0)" ::: "memory");

    int crow = l4 << 2;
    int ccol = lane & 15;
#pragma unroll
    for (int i = 0; i < 8; i++) {
#pragma unroll
        for (int q = 0; q < 4; q++) {
            size_t gm = (size_t)bm * 256 + wmB + i * 16 + crow;
            size_t gn = (size_t)bn * 256 + wnB + q * 16 + ccol;
            float bsv = bias[gn];
#pragma unroll
            for (int r = 0; r < 4; r++) {
                float v = acc[i][q][r] + bsv;
                size_t off = (gm + r) * (size_t)N + gn;
                if (EPI == 0) {
                    float g = 1.f / (1.f + __expf(-v));
                    ((float*)Coutv)[off] = g * extra[off];
                } else if (EPI == 1) {
                    ((unsigned short*)Coutv)[off] = f2bf(v > 0.f ? v : 0.f);
                } else {
                    ((float*)Coutv)[off] = v + extra[off];
                }
            }
        }
    }
}

// ---------- launch ----------
extern "C" void kernel_launch(void* const* d_in, const int* in_sizes, int n_in,
                              void* d_out, int out_size, void* d_ws, size_t ws_size,
                              hipStream_t stream) {
    const float* x   = (const float*)d_in[0];  // (B,T,C) fp32
    const float* n1w = (const float*)d_in[1];  // (C)
    const float* w1  = (const float*)d_in[2];  // (C,C)
    const float* b1  = (const float*)d_in[3];  // (C)
    const float* n2w = (const float*)d_in[4];  // (C)
    const float* w21 = (const float*)d_in[5];  // (C,E)
    const float* b21 = (const float*)d_in[6];  // (E)
    const float* w22 = (const float*)d_in[7];  // (E,C)
    const float* b22 = (const float*)d_in[8];  // (C)
    float* out = (float*)d_out;                // (B,T,C) fp32

    char* ws = (char*)d_ws;
    const size_t MB = 1024ull * 1024ull;
    unsigned short* state = (unsigned short*)(ws);            // 32MB bf16; reused as hnorm
    unsigned short* w1T   = (unsigned short*)(ws + 32 * MB);  // 2MB  (C x C) bf16
    unsigned short* w21T  = (unsigned short*)(ws + 34 * MB);  // 8MB  (E x C) bf16
    unsigned short* w22T  = (unsigned short*)(ws + 42 * MB);  // 8MB  (C x E) bf16
    float* P              = (float*)(ws + 50 * MB);           // 1MB
    float* rinv           = (float*)(ws + 51 * MB);           // 64KB
    unsigned short* h     = (unsigned short*)(ws + 52 * MB);  // up to 128MB bf16 (sliced)
    float* out1 = out;  // gate*x lives in d_out (fp32); G3 reads then overwrites per-element

    int slice_rows = Mdim;
    while (52 * MB + (size_t)slice_rows * Edim * 2 > ws_size && slice_rows > 1024)
        slice_rows >>= 1;

    // weights -> bf16 (N x K)
    transpose_f2b<<<dim3(Cdim / 32, Cdim / 32), 256, 0, stream>>>(w1, w1T, Cdim, Cdim);
    transpose_f2b<<<dim3(Edim / 32, Cdim / 32), 256, 0, stream>>>(w21, w21T, Cdim, Edim);
    transpose_f2b<<<dim3(Cdim / 32, Edim / 32), 256, 0, stream>>>(w22, w22T, Edim, Cdim);

    // fused rmsnorm1-rinv + chunk sums (one HBM pass over x)
    rms_chunk<<<256, 256, 0, stream>>>(x, n1w, rinv, P);

    // cumsum with folded prefix + triangular scaler -> bf16 state
    cumsum_state<<<1024, 256, 0, stream>>>(x, rinv, n1w, P, state);

    // G1: out1 = sigmoid(state @ w1 + b1) * x   (fp32 out into d_out)
    gemm8<0><<<dim3((Mdim / 256) * (Cdim / 256)), 512, 0, stream>>>(
        state, w1T, b1, x, out1, Cdim, Cdim);

    // rmsnorm2(out1) -> bf16 hnorm (reuse state buffer)
    rmsnorm_f2b<<<Mdim, 256, 0, stream>>>(out1, n2w, state);

    // G2 / G3 sliced over M to bound the h buffer
    for (int m0 = 0; m0 < Mdim; m0 += slice_rows) {
        gemm8<1><<<dim3((slice_rows / 256) * (Edim / 256)), 512, 0, stream>>>(
            state + (size_t)m0 * Cdim, w21T, b21, nullptr, h, Edim, Cdim);
        gemm8<2><<<dim3((slice_rows / 256) * (Cdim / 256)), 512, 0, stream>>>(
            h, w22T, b22, out1 + (size_t)m0 * Cdim, out + (size_t)m0 * Cdim,
            Cdim, Edim);
    }
}